// Round 5
// baseline (1144.407 us; speedup 1.0000x reference)
//
#include <hip/hip_runtime.h>

// MS-SSIM loss, 5 levels, fused per-level kernel.
// R5: R3 control flow (NO early load issue -- R4's 48-reg early issue caused a
//     scheduling pathology: VALUBusy 36->25%, +78us) +
//     pitch 63, no wred array -> LDS 32,760 B -> 5 blocks/CU (20 waves, 62.5% cap)
//     (was 34,816 -> 4 blocks; stalls dominate: 64% of level-0 time) +
//     padded pyramid levels 1-4 (8 zero cols each side) + zpad row-select so
//     every block except level-0 col-edge blocks takes the uniform float4 path +
//     TH=8 instantiation for grid-starved levels 3-4 (2x blocks).
// Bank math: phase-H b32 writes addr r*63+col, r-major lanes, step 63==31 mod 32
//   -> spread; phase-V column reads banks = c mod 32 -> exact 2-way (free).

#define TW 64
#define NIMG 48                // 16 * 3
#define HPITCH 63

template <int TH>
__global__ __launch_bounds__(256, 5) void ssim_level_kernel(
    const float* __restrict__ x, const float* __restrict__ y,
    long imgStride, int rowStride,
    float* __restrict__ dsx, float* __restrict__ dsy,
    long dsImgStride, int dsRowStride,
    const float* __restrict__ zpad,
    float* __restrict__ sum_out, int H, int W, int pad, int do_ds)
{
    constexpr int HHALO = TH + 10;
    constexpr int PLANE = HHALO * HPITCH;

    const float G[11] = {
        0.00102839f, 0.00759877f, 0.03600077f, 0.10936069f, 0.21300539f,
        0.26601173f, 0.21300539f, 0.10936069f, 0.03600077f, 0.00759877f,
        0.00102839f};
    const float C1 = 4.0e-4f;
    const float C2 = 3.6e-3f;

    __shared__ __align__(16) float hfT[5 * PLANE]; // TH=16: 32,760 B

    const int t   = threadIdx.x;
    const int img = blockIdx.z;
    const int C0  = blockIdx.x * TW;
    const int R0  = blockIdx.y * TH;
    const float* xi = x + (long)img * imgStride;
    const float* yi = y + (long)img * imgStride;

    // ---- fused avg-pool 2x2 for next level ----
    if (do_ds) {
        const int dsW = W >> 1, dsH = H >> 1;
        const int dr = t >> 5, dc = t & 31;
        const int gr2 = (R0 >> 1) + dr;
        const int gc2 = (C0 >> 1) + dc;
        if (dr < (TH >> 1) && gr2 < dsH && gc2 < dsW) {
            const float* sx = xi + (long)(2 * gr2) * rowStride + 2 * gc2;
            const float* sy = yi + (long)(2 * gr2) * rowStride + 2 * gc2;
            const float2 a0 = *reinterpret_cast<const float2*>(sx);
            const float2 a1 = *reinterpret_cast<const float2*>(sx + rowStride);
            const float2 b0 = *reinterpret_cast<const float2*>(sy);
            const float2 b1 = *reinterpret_cast<const float2*>(sy + rowStride);
            const long o = (long)img * dsImgStride + (long)gr2 * dsRowStride + gc2;
            dsx[o] = 0.25f * (a0.x + a0.y + a1.x + a1.y);
            dsy[o] = 0.25f * (b0.x + b0.y + b1.x + b1.y);
        }
    }

    // ---- Phase H: HHALO rows x 8 col-octets, r-major lanes ----
    if (t < HHALO * (TW / 8)) {
        const int r  = t % HHALO;
        const int q  = t / HHALO;
        const int gr = R0 + r - 5;
        const bool rok = ((unsigned)gr < (unsigned)H);
        const int gc0 = C0 + (q << 3) - 8;     // taps use [gc0+3, gc0+21)
        const bool fastp = pad || ((C0 >= 8) && (C0 + TW + 8 <= W)); // block-uniform

        float xv[24], yv[24];
        if (fastp) {
            const float* px = rok ? (xi + (long)gr * rowStride + gc0) : zpad;
            const float* py = rok ? (yi + (long)gr * rowStride + gc0) : zpad;
#pragma unroll
            for (int v = 0; v < 6; ++v) {
                const float4 a = reinterpret_cast<const float4*>(px)[v];
                const float4 b = reinterpret_cast<const float4*>(py)[v];
                xv[4 * v + 0] = a.x; xv[4 * v + 1] = a.y;
                xv[4 * v + 2] = a.z; xv[4 * v + 3] = a.w;
                yv[4 * v + 0] = b.x; yv[4 * v + 1] = b.y;
                yv[4 * v + 2] = b.z; yv[4 * v + 3] = b.w;
            }
        } else {
            const float* xrow = xi + (long)gr * rowStride;
            const float* yrow = yi + (long)gr * rowStride;
#pragma unroll
            for (int k = 3; k < 21; ++k) {
                const int gc = gc0 + k;
                const bool ok = rok && ((unsigned)gc < (unsigned)W);
                xv[k] = ok ? xrow[gc] : 0.0f;
                yv[k] = ok ? yrow[gc] : 0.0f;
            }
        }

        float xx[18], yy[18], xy[18];
#pragma unroll
        for (int k = 0; k < 18; ++k) {
            const float a = xv[k + 3], b = yv[k + 3];
            xx[k] = a * a; yy[k] = b * b; xy[k] = a * b;
        }

        float* hp = &hfT[r * HPITCH + (q << 3)];
#pragma unroll
        for (int j = 0; j < 8; ++j) {
            float sx = 0.f, sy = 0.f, sxx = 0.f, syy = 0.f, sxy = 0.f;
#pragma unroll
            for (int k = 0; k < 11; ++k) {
                const float g = G[k];
                sx  = fmaf(g, xv[j + k + 3], sx);
                sy  = fmaf(g, yv[j + k + 3], sy);
                sxx = fmaf(g, xx[j + k], sxx);
                syy = fmaf(g, yy[j + k], syy);
                sxy = fmaf(g, xy[j + k], sxy);
            }
            hp[0 * PLANE + j] = sx;
            hp[1 * PLANE + j] = sy;
            hp[2 * PLANE + j] = sxx;
            hp[3 * PLANE + j] = syy;
            hp[4 * PLANE + j] = sxy;
        }
    }
    __syncthreads();

    // ---- Phase V: thread = (col, row strip of TH/4); scalar column reads ----
    const int c   = t & 63;
    const int rr0 = (t >> 6) * (TH / 4);
    float acc[5][TH / 4];
#pragma unroll
    for (int f = 0; f < 5; ++f) {
        const float* hp = &hfT[f * PLANE + rr0 * HPITCH + c];
        float hv[10 + TH / 4];
#pragma unroll
        for (int k = 0; k < 10 + TH / 4; ++k) hv[k] = hp[k * HPITCH];
#pragma unroll
        for (int i = 0; i < TH / 4; ++i) {
            float a = 0.f;
#pragma unroll
            for (int k = 0; k < 11; ++k) a = fmaf(G[k], hv[i + k], a);
            acc[f][i] = a;
        }
    }

    float local = 0.f;
    const int gc = C0 + c;
#pragma unroll
    for (int i = 0; i < TH / 4; ++i) {
        const int gr2 = R0 + rr0 + i;
        if (gr2 < H && gc < W) {
            const float mu1 = acc[0][i], mu2 = acc[1][i];
            const float mu1s = mu1 * mu1, mu2s = mu2 * mu2, m12 = mu1 * mu2;
            const float s1  = acc[2][i] - mu1s;
            const float s2  = acc[3][i] - mu2s;
            const float s12 = acc[4][i] - m12;
            const float num = (2.f * m12 + C1) * (2.f * s12 + C2);
            const float den = (mu1s + mu2s + C1) * (s1 + s2 + C2);
            local += num * __builtin_amdgcn_rcpf(den + 1e-8f);
        }
    }

    // ---- wave shuffle reduce -> one atomicAdd per wave (no LDS) ----
#pragma unroll
    for (int off = 32; off > 0; off >>= 1) local += __shfl_down(local, off, 64);
    if ((t & 63) == 0) atomicAdd(sum_out, local);
}

__global__ void finalize_kernel(const float* __restrict__ sums,
                                float* __restrict__ out)
{
    if (threadIdx.x == 0 && blockIdx.x == 0) {
        const float w[5] = {0.0448f, 0.2856f, 0.3001f, 0.2363f, 0.1333f};
        const float wsum = w[0] + w[1] + w[2] + w[3] + w[4];
        float acc = 0.f;
#pragma unroll
        for (int i = 0; i < 5; ++i) {
            const int d = 512 >> i;
            const float cnt = (float)NIMG * (float)d * (float)d;
            acc += (w[i] / wsum) * (sums[i] / cnt);
        }
        out[0] = 1.0f - acc;
    }
}

extern "C" void kernel_launch(void* const* d_in, const int* in_sizes, int n_in,
                              void* d_out, int out_size, void* d_ws, size_t ws_size,
                              hipStream_t stream)
{
    const float* pred = (const float*)d_in[0];
    const float* targ = (const float*)d_in[1];
    float* out = (float*)d_out;
    float* ws  = (float*)d_ws;

    // padded pyramid: stride = W + 16 (8 zero cols each side)
    const long S1 = 256L * 272, S2 = 128L * 144, S3 = 64L * 80, S4 = 32L * 48;

    float* sums = ws;                       // 16 floats
    float* zpad = ws + 16;                  // 640 zero floats (row-OOB page)
    float* x1 = ws + 16 + 640;
    float* y1 = x1 + NIMG * S1;
    float* x2 = y1 + NIMG * S1;
    float* y2 = x2 + NIMG * S2;
    float* x3 = y2 + NIMG * S2;
    float* y3 = x3 + NIMG * S3;
    float* x4 = y3 + NIMG * S3;
    float* y4 = x4 + NIMG * S4;
    float* wsEnd = y4 + NIMG * S4 + 64;

    hipMemsetAsync(ws, 0, (size_t)(wsEnd - ws) * sizeof(float), stream);

    // level 0: unpadded harness input
    { dim3 g(8, 32, NIMG);
      ssim_level_kernel<16><<<g, 256, 0, stream>>>(pred, targ, 512L * 512, 512,
          x1 + 8, y1 + 8, S1, 272, zpad, sums + 0, 512, 512, 0, 1); }
    // level 1
    { dim3 g(4, 16, NIMG);
      ssim_level_kernel<16><<<g, 256, 0, stream>>>(x1 + 8, y1 + 8, S1, 272,
          x2 + 8, y2 + 8, S2, 144, zpad, sums + 1, 256, 256, 1, 1); }
    // level 2
    { dim3 g(2, 8, NIMG);
      ssim_level_kernel<16><<<g, 256, 0, stream>>>(x2 + 8, y2 + 8, S2, 144,
          x3 + 8, y3 + 8, S3, 80, zpad, sums + 2, 128, 128, 1, 1); }
    // level 3: TH=8 -> 384 blocks
    { dim3 g(1, 8, NIMG);
      ssim_level_kernel<8><<<g, 256, 0, stream>>>(x3 + 8, y3 + 8, S3, 80,
          x4 + 8, y4 + 8, S4, 48, zpad, sums + 3, 64, 64, 1, 1); }
    // level 4: TH=8 -> 192 blocks, no downsample
    { dim3 g(1, 4, NIMG);
      ssim_level_kernel<8><<<g, 256, 0, stream>>>(x4 + 8, y4 + 8, S4, 48,
          nullptr, nullptr, 0, 0, zpad, sums + 4, 32, 32, 1, 0); }

    finalize_kernel<<<1, 64, 0, stream>>>(sums, out);
}

// Round 6
// 1093.357 us; speedup vs baseline: 1.0467x; 1.0467x over previous
//
#include <hip/hip_runtime.h>

// MS-SSIM loss, 5 levels, fused per-level kernel.
// R6: R3 control flow. CRITICAL: __launch_bounds__ 2nd arg stays 4 -- the
//     compiler's VGPR cap is 256/min_waves (bound 5 -> cap 48 -> spilled the
//     phase-H window arrays -> 440 MB scratch traffic, 8.5% VALUBusy in R5).
//     Occupancy is raised via LDS instead: pitch 62 -> 32,240 B <= 32 KB ->
//     5 blocks/CU at 64 VGPRs (512/SIMD pool allows 8 waves).
// Bank math (pitch 62): phase-H float2 writes, r-major lanes, bank step
//     30 mod 32 -> spread (~2-way, free); phase-V column reads bank = c mod 32
//     -> exact 2-way (free). R3 measured 1.7e6 conflicts with this family.
// Padded pyramid levels 1-4 (8 zero cols each side) + zpad row-select: every
// block except level-0 col-edge blocks takes the uniform float4 path.
// TH=8 instantiation for grid-starved levels 3-4.

#define TW 64
#define NIMG 48                // 16 * 3
#define HPITCH 62              // even (float2-aligned), 30 mod 32 bank step

template <int TH>
__global__ __launch_bounds__(256, 4) void ssim_level_kernel(
    const float* __restrict__ x, const float* __restrict__ y,
    long imgStride, int rowStride,
    float* __restrict__ dsx, float* __restrict__ dsy,
    long dsImgStride, int dsRowStride,
    const float* __restrict__ zpad,
    float* __restrict__ sum_out, int H, int W, int pad, int do_ds)
{
    constexpr int HHALO = TH + 10;
    constexpr int PLANE = HHALO * HPITCH;

    const float G[11] = {
        0.00102839f, 0.00759877f, 0.03600077f, 0.10936069f, 0.21300539f,
        0.26601173f, 0.21300539f, 0.10936069f, 0.03600077f, 0.00759877f,
        0.00102839f};
    const float C1 = 4.0e-4f;
    const float C2 = 3.6e-3f;

    __shared__ __align__(16) float hfT[5 * PLANE]; // TH=16: 32,240 B

    const int t   = threadIdx.x;
    const int img = blockIdx.z;
    const int C0  = blockIdx.x * TW;
    const int R0  = blockIdx.y * TH;
    const float* xi = x + (long)img * imgStride;
    const float* yi = y + (long)img * imgStride;

    // ---- fused avg-pool 2x2 for next level ----
    if (do_ds) {
        const int dsW = W >> 1, dsH = H >> 1;
        const int dr = t >> 5, dc = t & 31;
        const int gr2 = (R0 >> 1) + dr;
        const int gc2 = (C0 >> 1) + dc;
        if (dr < (TH >> 1) && gr2 < dsH && gc2 < dsW) {
            const float* sx = xi + (long)(2 * gr2) * rowStride + 2 * gc2;
            const float* sy = yi + (long)(2 * gr2) * rowStride + 2 * gc2;
            const float2 a0 = *reinterpret_cast<const float2*>(sx);
            const float2 a1 = *reinterpret_cast<const float2*>(sx + rowStride);
            const float2 b0 = *reinterpret_cast<const float2*>(sy);
            const float2 b1 = *reinterpret_cast<const float2*>(sy + rowStride);
            const long o = (long)img * dsImgStride + (long)gr2 * dsRowStride + gc2;
            dsx[o] = 0.25f * (a0.x + a0.y + a1.x + a1.y);
            dsy[o] = 0.25f * (b0.x + b0.y + b1.x + b1.y);
        }
    }

    // ---- Phase H: HHALO rows x 8 col-octets, r-major lanes ----
    if (t < HHALO * (TW / 8)) {
        const int r  = t % HHALO;
        const int q  = t / HHALO;
        const int gr = R0 + r - 5;
        const bool rok = ((unsigned)gr < (unsigned)H);
        const int gc0 = C0 + (q << 3) - 8;     // taps use [gc0+3, gc0+21)
        const bool fastp = pad || ((C0 >= 8) && (C0 + TW + 8 <= W)); // block-uniform

        float xv[24], yv[24];
        if (fastp) {
            const float* px = rok ? (xi + (long)gr * rowStride + gc0) : zpad;
            const float* py = rok ? (yi + (long)gr * rowStride + gc0) : zpad;
#pragma unroll
            for (int v = 0; v < 6; ++v) {
                const float4 a = reinterpret_cast<const float4*>(px)[v];
                const float4 b = reinterpret_cast<const float4*>(py)[v];
                xv[4 * v + 0] = a.x; xv[4 * v + 1] = a.y;
                xv[4 * v + 2] = a.z; xv[4 * v + 3] = a.w;
                yv[4 * v + 0] = b.x; yv[4 * v + 1] = b.y;
                yv[4 * v + 2] = b.z; yv[4 * v + 3] = b.w;
            }
        } else {
            const float* xrow = xi + (long)gr * rowStride;
            const float* yrow = yi + (long)gr * rowStride;
#pragma unroll
            for (int k = 3; k < 21; ++k) {
                const int gc = gc0 + k;
                const bool ok = rok && ((unsigned)gc < (unsigned)W);
                xv[k] = ok ? xrow[gc] : 0.0f;
                yv[k] = ok ? yrow[gc] : 0.0f;
            }
        }

        float xx[18], yy[18], xy[18];
#pragma unroll
        for (int k = 0; k < 18; ++k) {
            const float a = xv[k + 3], b = yv[k + 3];
            xx[k] = a * a; yy[k] = b * b; xy[k] = a * b;
        }

        float hx[8], hy[8], hxx[8], hyy[8], hxy[8];
#pragma unroll
        for (int j = 0; j < 8; ++j) {
            float sx = 0.f, sy = 0.f, sxx = 0.f, syy = 0.f, sxy = 0.f;
#pragma unroll
            for (int k = 0; k < 11; ++k) {
                const float g = G[k];
                sx  = fmaf(g, xv[j + k + 3], sx);
                sy  = fmaf(g, yv[j + k + 3], sy);
                sxx = fmaf(g, xx[j + k], sxx);
                syy = fmaf(g, yy[j + k], syy);
                sxy = fmaf(g, xy[j + k], sxy);
            }
            hx[j] = sx; hy[j] = sy; hxx[j] = sxx; hyy[j] = syy; hxy[j] = sxy;
        }
        float* hp = &hfT[r * HPITCH + (q << 3)];  // even word offset -> b64 ok
#pragma unroll
        for (int p = 0; p < 4; ++p) {
            reinterpret_cast<float2*>(hp + 0 * PLANE)[p] = make_float2(hx[2*p],  hx[2*p+1]);
            reinterpret_cast<float2*>(hp + 1 * PLANE)[p] = make_float2(hy[2*p],  hy[2*p+1]);
            reinterpret_cast<float2*>(hp + 2 * PLANE)[p] = make_float2(hxx[2*p], hxx[2*p+1]);
            reinterpret_cast<float2*>(hp + 3 * PLANE)[p] = make_float2(hyy[2*p], hyy[2*p+1]);
            reinterpret_cast<float2*>(hp + 4 * PLANE)[p] = make_float2(hxy[2*p], hxy[2*p+1]);
        }
    }
    __syncthreads();

    // ---- Phase V: thread = (col, row strip of TH/4); scalar column reads ----
    const int c   = t & 63;
    const int rr0 = (t >> 6) * (TH / 4);     // wave-uniform
    float acc[5][TH / 4];
#pragma unroll
    for (int f = 0; f < 5; ++f) {
        const float* hp = &hfT[f * PLANE + rr0 * HPITCH + c];
        float hv[10 + TH / 4];
#pragma unroll
        for (int k = 0; k < 10 + TH / 4; ++k) hv[k] = hp[k * HPITCH];
#pragma unroll
        for (int i = 0; i < TH / 4; ++i) {
            float a = 0.f;
#pragma unroll
            for (int k = 0; k < 11; ++k) a = fmaf(G[k], hv[i + k], a);
            acc[f][i] = a;
        }
    }

    float local = 0.f;
    const int gc = C0 + c;
#pragma unroll
    for (int i = 0; i < TH / 4; ++i) {
        const int gr2 = R0 + rr0 + i;
        if (gr2 < H && gc < W) {
            const float mu1 = acc[0][i], mu2 = acc[1][i];
            const float mu1s = mu1 * mu1, mu2s = mu2 * mu2, m12 = mu1 * mu2;
            const float s1  = acc[2][i] - mu1s;
            const float s2  = acc[3][i] - mu2s;
            const float s12 = acc[4][i] - m12;
            const float num = (2.f * m12 + C1) * (2.f * s12 + C2);
            const float den = (mu1s + mu2s + C1) * (s1 + s2 + C2);
            local += num * __builtin_amdgcn_rcpf(den + 1e-8f);
        }
    }

    // ---- wave shuffle reduce -> one atomicAdd per wave ----
#pragma unroll
    for (int off = 32; off > 0; off >>= 1) local += __shfl_down(local, off, 64);
    if ((t & 63) == 0) atomicAdd(sum_out, local);
}

__global__ void finalize_kernel(const float* __restrict__ sums,
                                float* __restrict__ out)
{
    if (threadIdx.x == 0 && blockIdx.x == 0) {
        const float w[5] = {0.0448f, 0.2856f, 0.3001f, 0.2363f, 0.1333f};
        const float wsum = w[0] + w[1] + w[2] + w[3] + w[4];
        float acc = 0.f;
#pragma unroll
        for (int i = 0; i < 5; ++i) {
            const int d = 512 >> i;
            const float cnt = (float)NIMG * (float)d * (float)d;
            acc += (w[i] / wsum) * (sums[i] / cnt);
        }
        out[0] = 1.0f - acc;
    }
}

extern "C" void kernel_launch(void* const* d_in, const int* in_sizes, int n_in,
                              void* d_out, int out_size, void* d_ws, size_t ws_size,
                              hipStream_t stream)
{
    const float* pred = (const float*)d_in[0];
    const float* targ = (const float*)d_in[1];
    float* out = (float*)d_out;
    float* ws  = (float*)d_ws;

    // padded pyramid: stride = W + 16 (8 zero cols each side)
    const long S1 = 256L * 272, S2 = 128L * 144, S3 = 64L * 80, S4 = 32L * 48;

    float* sums = ws;                       // 16 floats
    float* zpad = ws + 16;                  // 640 zero floats (row-OOB page)
    float* x1 = ws + 16 + 640;
    float* y1 = x1 + NIMG * S1;
    float* x2 = y1 + NIMG * S1;
    float* y2 = x2 + NIMG * S2;
    float* x3 = y2 + NIMG * S2;
    float* y3 = x3 + NIMG * S3;
    float* x4 = y3 + NIMG * S3;
    float* y4 = x4 + NIMG * S4;
    float* wsEnd = y4 + NIMG * S4 + 64;

    hipMemsetAsync(ws, 0, (size_t)(wsEnd - ws) * sizeof(float), stream);

    // level 0: unpadded harness input
    { dim3 g(8, 32, NIMG);
      ssim_level_kernel<16><<<g, 256, 0, stream>>>(pred, targ, 512L * 512, 512,
          x1 + 8, y1 + 8, S1, 272, zpad, sums + 0, 512, 512, 0, 1); }
    // level 1
    { dim3 g(4, 16, NIMG);
      ssim_level_kernel<16><<<g, 256, 0, stream>>>(x1 + 8, y1 + 8, S1, 272,
          x2 + 8, y2 + 8, S2, 144, zpad, sums + 1, 256, 256, 1, 1); }
    // level 2
    { dim3 g(2, 8, NIMG);
      ssim_level_kernel<16><<<g, 256, 0, stream>>>(x2 + 8, y2 + 8, S2, 144,
          x3 + 8, y3 + 8, S3, 80, zpad, sums + 2, 128, 128, 1, 1); }
    // level 3: TH=8 -> 384 blocks
    { dim3 g(1, 8, NIMG);
      ssim_level_kernel<8><<<g, 256, 0, stream>>>(x3 + 8, y3 + 8, S3, 80,
          x4 + 8, y4 + 8, S4, 48, zpad, sums + 3, 64, 64, 1, 1); }
    // level 4: TH=8 -> 192 blocks, no downsample
    { dim3 g(1, 4, NIMG);
      ssim_level_kernel<8><<<g, 256, 0, stream>>>(x4 + 8, y4 + 8, S4, 48,
          nullptr, nullptr, 0, 0, zpad, sums + 4, 32, 32, 1, 0); }

    finalize_kernel<<<1, 64, 0, stream>>>(sums, out);
}

// Round 7
// 297.738 us; speedup vs baseline: 3.8437x; 3.6722x over previous
//
#include <hip/hip_runtime.h>

// MS-SSIM loss, 5 levels, fused per-level kernel.
// R7: THE BOTTLENECK WAS SAME-ADDRESS ATOMICS. Every round R1-R6 fits
//     ~14 ns per device-scope fp32 atomicAdd to one address (cross-XCD
//     line serialization): R6 = 49,152 atomics x 14.7ns = 723us @ 8.6%
//     VALUBusy; R3 = 12,288 x ~14ns = 175us (was ALREADY atomic-bound).
//     Fix: per-wave atomicAdd into 256 SPREAD slots per level
//     (192 atomics/slot for L0 -> ~3us per chain, parallel across slots).
// Carried from R3-R6 (all verified by counters):
//  - pitch-62 row-major LDS (conflicts 2.4e7 -> 1.7e6), 32,240 B -> 5 blk/CU
//  - __launch_bounds__ 2nd arg 4: bound 5 => VGPR cap 48 => spill (R5)
//  - padded pyramid levels 1-4 + zpad row-select: uniform float4 path
//  - no early load issue (R4: scheduling pathology, VALUBusy 36->25%)
//  - TH=8 for grid-starved levels 3-4

#define TW 64
#define NIMG 48                // 16 * 3
#define HPITCH 62              // even (float2-aligned), bank step 30 mod 32
#define NSLOT 256              // spread-atomic slots per level

template <int TH>
__global__ __launch_bounds__(256, 4) void ssim_level_kernel(
    const float* __restrict__ x, const float* __restrict__ y,
    long imgStride, int rowStride,
    float* __restrict__ dsx, float* __restrict__ dsy,
    long dsImgStride, int dsRowStride,
    const float* __restrict__ zpad,
    float* __restrict__ slots, int H, int W, int pad, int do_ds)
{
    constexpr int HHALO = TH + 10;
    constexpr int PLANE = HHALO * HPITCH;

    const float G[11] = {
        0.00102839f, 0.00759877f, 0.03600077f, 0.10936069f, 0.21300539f,
        0.26601173f, 0.21300539f, 0.10936069f, 0.03600077f, 0.00759877f,
        0.00102839f};
    const float C1 = 4.0e-4f;
    const float C2 = 3.6e-3f;

    __shared__ __align__(16) float hfT[5 * PLANE]; // TH=16: 32,240 B

    const int t   = threadIdx.x;
    const int img = blockIdx.z;
    const int C0  = blockIdx.x * TW;
    const int R0  = blockIdx.y * TH;
    const float* xi = x + (long)img * imgStride;
    const float* yi = y + (long)img * imgStride;

    // ---- fused avg-pool 2x2 for next level ----
    if (do_ds) {
        const int dsW = W >> 1, dsH = H >> 1;
        const int dr = t >> 5, dc = t & 31;
        const int gr2 = (R0 >> 1) + dr;
        const int gc2 = (C0 >> 1) + dc;
        if (dr < (TH >> 1) && gr2 < dsH && gc2 < dsW) {
            const float* sx = xi + (long)(2 * gr2) * rowStride + 2 * gc2;
            const float* sy = yi + (long)(2 * gr2) * rowStride + 2 * gc2;
            const float2 a0 = *reinterpret_cast<const float2*>(sx);
            const float2 a1 = *reinterpret_cast<const float2*>(sx + rowStride);
            const float2 b0 = *reinterpret_cast<const float2*>(sy);
            const float2 b1 = *reinterpret_cast<const float2*>(sy + rowStride);
            const long o = (long)img * dsImgStride + (long)gr2 * dsRowStride + gc2;
            dsx[o] = 0.25f * (a0.x + a0.y + a1.x + a1.y);
            dsy[o] = 0.25f * (b0.x + b0.y + b1.x + b1.y);
        }
    }

    // ---- Phase H: HHALO rows x 8 col-octets, r-major lanes ----
    if (t < HHALO * (TW / 8)) {
        const int r  = t % HHALO;
        const int q  = t / HHALO;
        const int gr = R0 + r - 5;
        const bool rok = ((unsigned)gr < (unsigned)H);
        const int gc0 = C0 + (q << 3) - 8;     // taps use [gc0+3, gc0+21)
        const bool fastp = pad || ((C0 >= 8) && (C0 + TW + 8 <= W)); // block-uniform

        float xv[24], yv[24];
        if (fastp) {
            const float* px = rok ? (xi + (long)gr * rowStride + gc0) : zpad;
            const float* py = rok ? (yi + (long)gr * rowStride + gc0) : zpad;
#pragma unroll
            for (int v = 0; v < 6; ++v) {
                const float4 a = reinterpret_cast<const float4*>(px)[v];
                const float4 b = reinterpret_cast<const float4*>(py)[v];
                xv[4 * v + 0] = a.x; xv[4 * v + 1] = a.y;
                xv[4 * v + 2] = a.z; xv[4 * v + 3] = a.w;
                yv[4 * v + 0] = b.x; yv[4 * v + 1] = b.y;
                yv[4 * v + 2] = b.z; yv[4 * v + 3] = b.w;
            }
        } else {
            const float* xrow = xi + (long)gr * rowStride;
            const float* yrow = yi + (long)gr * rowStride;
#pragma unroll
            for (int k = 3; k < 21; ++k) {
                const int gc = gc0 + k;
                const bool ok = rok && ((unsigned)gc < (unsigned)W);
                xv[k] = ok ? xrow[gc] : 0.0f;
                yv[k] = ok ? yrow[gc] : 0.0f;
            }
        }

        float xx[18], yy[18], xy[18];
#pragma unroll
        for (int k = 0; k < 18; ++k) {
            const float a = xv[k + 3], b = yv[k + 3];
            xx[k] = a * a; yy[k] = b * b; xy[k] = a * b;
        }

        float hx[8], hy[8], hxx[8], hyy[8], hxy[8];
#pragma unroll
        for (int j = 0; j < 8; ++j) {
            float sx = 0.f, sy = 0.f, sxx = 0.f, syy = 0.f, sxy = 0.f;
#pragma unroll
            for (int k = 0; k < 11; ++k) {
                const float g = G[k];
                sx  = fmaf(g, xv[j + k + 3], sx);
                sy  = fmaf(g, yv[j + k + 3], sy);
                sxx = fmaf(g, xx[j + k], sxx);
                syy = fmaf(g, yy[j + k], syy);
                sxy = fmaf(g, xy[j + k], sxy);
            }
            hx[j] = sx; hy[j] = sy; hxx[j] = sxx; hyy[j] = syy; hxy[j] = sxy;
        }
        float* hp = &hfT[r * HPITCH + (q << 3)];  // even word offset -> b64 ok
#pragma unroll
        for (int p = 0; p < 4; ++p) {
            reinterpret_cast<float2*>(hp + 0 * PLANE)[p] = make_float2(hx[2*p],  hx[2*p+1]);
            reinterpret_cast<float2*>(hp + 1 * PLANE)[p] = make_float2(hy[2*p],  hy[2*p+1]);
            reinterpret_cast<float2*>(hp + 2 * PLANE)[p] = make_float2(hxx[2*p], hxx[2*p+1]);
            reinterpret_cast<float2*>(hp + 3 * PLANE)[p] = make_float2(hyy[2*p], hyy[2*p+1]);
            reinterpret_cast<float2*>(hp + 4 * PLANE)[p] = make_float2(hxy[2*p], hxy[2*p+1]);
        }
    }
    __syncthreads();

    // ---- Phase V: thread = (col, row strip of TH/4); scalar column reads ----
    const int c   = t & 63;
    const int rr0 = (t >> 6) * (TH / 4);     // wave-uniform
    float acc[5][TH / 4];
#pragma unroll
    for (int f = 0; f < 5; ++f) {
        const float* hp = &hfT[f * PLANE + rr0 * HPITCH + c];
        float hv[10 + TH / 4];
#pragma unroll
        for (int k = 0; k < 10 + TH / 4; ++k) hv[k] = hp[k * HPITCH];
#pragma unroll
        for (int i = 0; i < TH / 4; ++i) {
            float a = 0.f;
#pragma unroll
            for (int k = 0; k < 11; ++k) a = fmaf(G[k], hv[i + k], a);
            acc[f][i] = a;
        }
    }

    float local = 0.f;
    const int gc = C0 + c;
#pragma unroll
    for (int i = 0; i < TH / 4; ++i) {
        const int gr2 = R0 + rr0 + i;
        if (gr2 < H && gc < W) {
            const float mu1 = acc[0][i], mu2 = acc[1][i];
            const float mu1s = mu1 * mu1, mu2s = mu2 * mu2, m12 = mu1 * mu2;
            const float s1  = acc[2][i] - mu1s;
            const float s2  = acc[3][i] - mu2s;
            const float s12 = acc[4][i] - m12;
            const float num = (2.f * m12 + C1) * (2.f * s12 + C2);
            const float den = (mu1s + mu2s + C1) * (s1 + s2 + C2);
            local += num * __builtin_amdgcn_rcpf(den + 1e-8f);
        }
    }

    // ---- wave shuffle reduce -> one atomicAdd per wave into a SPREAD slot ----
#pragma unroll
    for (int off = 32; off > 0; off >>= 1) local += __shfl_down(local, off, 64);
    if ((t & 63) == 0) {
        const int bid = (blockIdx.z * gridDim.y + blockIdx.y) * gridDim.x + blockIdx.x;
        const int slot = ((bid << 2) | (t >> 6)) & (NSLOT - 1);
        atomicAdd(slots + slot, local);
    }
}

__global__ void finalize_kernel(const float* __restrict__ slots,
                                float* __restrict__ out)
{
    const int t = threadIdx.x;          // 256 threads: one slot per thread
    const float w[5] = {0.0448f, 0.2856f, 0.3001f, 0.2363f, 0.1333f};
    const float wsum = w[0] + w[1] + w[2] + w[3] + w[4];
    float acc = 0.f;
#pragma unroll
    for (int lvl = 0; lvl < 5; ++lvl) {
        const int d = 512 >> lvl;
        const float cnt = (float)NIMG * (float)d * (float)d;
        acc += (w[lvl] / wsum) / cnt * slots[lvl * NSLOT + t];
    }
#pragma unroll
    for (int off = 32; off > 0; off >>= 1) acc += __shfl_down(acc, off, 64);
    __shared__ float p[4];
    if ((t & 63) == 0) p[t >> 6] = acc;
    __syncthreads();
    if (t == 0) out[0] = 1.0f - (p[0] + p[1] + p[2] + p[3]);
}

extern "C" void kernel_launch(void* const* d_in, const int* in_sizes, int n_in,
                              void* d_out, int out_size, void* d_ws, size_t ws_size,
                              hipStream_t stream)
{
    const float* pred = (const float*)d_in[0];
    const float* targ = (const float*)d_in[1];
    float* out = (float*)d_out;
    float* ws  = (float*)d_ws;

    // padded pyramid: stride = W + 16 (8 zero cols each side)
    const long S1 = 256L * 272, S2 = 128L * 144, S3 = 64L * 80, S4 = 32L * 48;

    float* slots = ws;                      // 5 * 256 floats
    float* zpad  = ws + 5 * NSLOT;          // 640 zero floats (row-OOB page)
    float* x1 = zpad + 640;
    float* y1 = x1 + NIMG * S1;
    float* x2 = y1 + NIMG * S1;
    float* y2 = x2 + NIMG * S2;
    float* x3 = y2 + NIMG * S2;
    float* y3 = x3 + NIMG * S3;
    float* x4 = y3 + NIMG * S3;
    float* y4 = x4 + NIMG * S4;
    float* wsEnd = y4 + NIMG * S4 + 64;

    hipMemsetAsync(ws, 0, (size_t)(wsEnd - ws) * sizeof(float), stream);

    // level 0: unpadded harness input
    { dim3 g(8, 32, NIMG);
      ssim_level_kernel<16><<<g, 256, 0, stream>>>(pred, targ, 512L * 512, 512,
          x1 + 8, y1 + 8, S1, 272, zpad, slots + 0 * NSLOT, 512, 512, 0, 1); }
    // level 1
    { dim3 g(4, 16, NIMG);
      ssim_level_kernel<16><<<g, 256, 0, stream>>>(x1 + 8, y1 + 8, S1, 272,
          x2 + 8, y2 + 8, S2, 144, zpad, slots + 1 * NSLOT, 256, 256, 1, 1); }
    // level 2
    { dim3 g(2, 8, NIMG);
      ssim_level_kernel<16><<<g, 256, 0, stream>>>(x2 + 8, y2 + 8, S2, 144,
          x3 + 8, y3 + 8, S3, 80, zpad, slots + 2 * NSLOT, 128, 128, 1, 1); }
    // level 3: TH=8 -> 384 blocks
    { dim3 g(1, 8, NIMG);
      ssim_level_kernel<8><<<g, 256, 0, stream>>>(x3 + 8, y3 + 8, S3, 80,
          x4 + 8, y4 + 8, S4, 48, zpad, slots + 3 * NSLOT, 64, 64, 1, 1); }
    // level 4: TH=8 -> 192 blocks, no downsample
    { dim3 g(1, 4, NIMG);
      ssim_level_kernel<8><<<g, 256, 0, stream>>>(x4 + 8, y4 + 8, S4, 48,
          nullptr, nullptr, 0, 0, zpad, slots + 4 * NSLOT, 32, 32, 1, 0); }

    finalize_kernel<<<1, 256, 0, stream>>>(slots, out);
}